// Round 12
// baseline (80.100 us; speedup 1.0000x reference)
//
#include <hip/hip_runtime.h>

// 20-qubit feature map, 4 layers (RX·RY per wire + CNOT chain), <Z_i> outputs.
// wire w <-> bit b=19-w. CNOT chain == gray perm P: new[y]=old[y^(y>>1)].
// Masked gate (P pending) on bit b: pairs z <-> z^m, m = b? 3<<(b-1) : 1;
// row-0 amp has y_b=0 where y_b = XOR_{j>=b} z_j. [R6-verified]
// R12 schedule (4 gate passes; EVERY pass = all-plain THEN all-masked — R11's
// failure was interleaving them; masked gates have controls on higher bits):
//  P1 (A, block H=z12..19): L1 product (perm folded) + plain L2 b0..11  [R8 verbatim]
//  P2 (B, block bb=z3..10, in-place): plain L2 b12..19 + masked L3 b12..19
//  P3 (A, gray-fold read): plain L3 b0..11 [R8 walk] + masked L4 b0..11
//  P4 (B): masked L4 b12..19 + expectation (2 perms pending -> pfx2 signs)
// Engine: 1024 thr x 4 amps (2 reg bits), butterflies reg<->lane, LDS trips
// permute only {reg,wave} bits (lane always addr bits 0..5 -> conflict-free).

#define NW 20

__device__ __forceinline__ float2 cmul(float2 a, float2 b) {
    return make_float2(a.x*b.x - a.y*b.y, a.x*b.y + a.y*b.x);
}

__device__ __forceinline__ void apply_gate(float2& a0, float2& a1,
                                           float2 u00, float2 u01,
                                           float2 u10, float2 u11) {
    float2 b0, b1;
    b0.x = u00.x*a0.x - u00.y*a0.y + u01.x*a1.x - u01.y*a1.y;
    b0.y = u00.x*a0.y + u00.y*a0.x + u01.x*a1.y + u01.y*a1.x;
    b1.x = u10.x*a0.x - u10.y*a0.y + u11.x*a1.x - u11.y*a1.y;
    b1.y = u10.x*a0.y + u10.y*a0.x + u11.x*a1.y + u11.y*a1.x;
    a0 = b0; a1 = b1;
}

__device__ __forceinline__ float2 shflx(float2 v, int m) {
    float2 r;
    r.x = __shfl_xor(v.x, m, 64);
    r.y = __shfl_xor(v.y, m, 64);
    return r;
}

// pfx2: bit b = XOR_{j>=b, j==b mod 2} x_j  == invgray^2 bit map [R6-verified]
__device__ __forceinline__ unsigned pfx2(unsigned x) {
    x ^= x >> 2; x ^= x >> 4; x ^= x >> 8; x ^= x >> 16; return x;
}

template<int A>
__device__ __forceinline__ void gate_regbit(float2 (&amp)[4], const float2* Gw) {
    float2 u00 = Gw[0], u01 = Gw[1], u10 = Gw[2], u11 = Gw[3];
    #pragma unroll
    for (int r = 0; r < 4; r++)
        if (!(r & (1 << A)))
            apply_gate(amp[r], amp[r | (1 << A)], u00, u01, u10, u11);
}

// butterfly: swap reg-bit A content with lane-bit LM content [R4-verified]
template<int A, int LM>
__device__ __forceinline__ void swap_reg_lane4(float2 (&amp)[4], unsigned lane) {
    bool hb = (lane & (unsigned)LM) != 0u;
    #pragma unroll
    for (int r = 0; r < 4; r++) {
        if (!(r & (1 << A))) {
            float2 lo = amp[r], hi = amp[r | (1 << A)];
            float2 xs = hb ? lo : hi;
            float2 ys = shflx(xs, LM);
            amp[r]            = hb ? ys : lo;
            amp[r | (1 << A)] = hb ? hi : ys;
        }
    }
}

// masked gate, pair mask M in regs; SEL = reg bit holding z_b; RH = reg bits of
// z_j (j>b); Rk = XOR of all non-reg z_j (j>b). [R6-verified semantics]
template<int M, int SEL, int RH>
__device__ __forceinline__ void gate_mreg(float2 (&amp)[4], const float2* Gw,
                                          unsigned Rk) {
    float2 u00 = Gw[0], u01 = Gw[1], u10 = Gw[2], u11 = Gw[3];
    #pragma unroll
    for (int r = 0; r < 4; r++) {
        if (r & SEL) continue;
        int rp = r ^ M;
        unsigned fl = (Rk + (unsigned)__popc((unsigned)r & (unsigned)RH)) & 1u;
        if (fl == 0u) apply_gate(amp[r], amp[rp], u00, u01, u10, u11);
        else          apply_gate(amp[rp], amp[r], u00, u01, u10, u11);
    }
}

// U = RY(x)*RX(x), half-angle. G[w*4 + r*2 + c] = U^w[r][c].
__device__ __forceinline__ void prep_Gs(const float* __restrict__ x, float2* Gs,
                                        unsigned t) {
    if (t < NW) {
        float h = 0.5f * x[t];
        float c = cosf(h), s = sinf(h);
        float cc = c*c, ss = s*s, cs = c*s;
        Gs[t*4+0] = make_float2(cc,  ss);
        Gs[t*4+1] = make_float2(-cs, -cs);
        Gs[t*4+2] = make_float2(cs,  -cs);
        Gs[t*4+3] = make_float2(cc,  -ss);
    }
}

// Masked chain m19..m12 (ONE perm pending). Shared by P2 and P4.
// ENTRY map: K={z18,z19}, l3=z12, l4=z13, l5=z11, w0=z14,w1=z15,w2=z16,w3=z17.
// EXIT  map: K(k0)=z12, K(k1)=z11; l3=z14, l4=z15, l5=z13; w0=z16..w3=z19.
__device__ __forceinline__ void masked_high(float2 (&amp)[4], float2* lds,
                                            const float2* Gs, unsigned lane,
                                            unsigned wv) {
    const unsigned w0 = wv & 1u, w1 = (wv >> 1) & 1u, w2 = (wv >> 2) & 1u, w3 = wv >> 3;
    const unsigned l3 = (lane >> 3) & 1u, l4 = (lane >> 4) & 1u, l5 = lane >> 5;
    const unsigned wpar = w0 ^ w1 ^ w2 ^ w3;
    // m19 {18,19}: SEL z19=k1, Rk = 0
    gate_mreg<3,2,0>(amp, Gs + 0*4, 0u);
    // Xa: K {z18,z19} -> {z17,z18}; w3 becomes z19
    #pragma unroll
    for (int k = 0; k < 4; k++) lds[lane | ((unsigned)k << 6) | (wv << 8)] = amp[k];
    __syncthreads();
    #pragma unroll
    for (int k = 0; k < 4; k++)
        amp[k] = lds[lane | ((unsigned)(k>>1) << 6) | (w3 << 7) | (w0 << 8)
                     | (w1 << 9) | (w2 << 10) | ((unsigned)(k&1) << 11)];
    __syncthreads();
    gate_mreg<3,2,0>(amp, Gs + 1*4, w3);              // m18 {17,18}: Rk=z19=w3
    // Xb: K -> {z16,z17}; w2 becomes z18
    #pragma unroll
    for (int k = 0; k < 4; k++) lds[lane | ((unsigned)k << 6) | (wv << 8)] = amp[k];
    __syncthreads();
    #pragma unroll
    for (int k = 0; k < 4; k++)
        amp[k] = lds[lane | ((unsigned)(k>>1) << 6) | (w2 << 7) | (w0 << 8)
                     | (w1 << 9) | ((unsigned)(k&1) << 10) | (w3 << 11)];
    __syncthreads();
    gate_mreg<3,2,0>(amp, Gs + 2*4, w2 ^ w3);         // m17 {16,17}: Rk=z18^z19
    // Xc: K -> {z15,z16}; w1 becomes z17
    #pragma unroll
    for (int k = 0; k < 4; k++) lds[lane | ((unsigned)k << 6) | (wv << 8)] = amp[k];
    __syncthreads();
    #pragma unroll
    for (int k = 0; k < 4; k++)
        amp[k] = lds[lane | ((unsigned)(k>>1) << 6) | (w1 << 7) | (w0 << 8)
                     | ((unsigned)(k&1) << 9) | (w2 << 10) | (w3 << 11)];
    __syncthreads();
    gate_mreg<3,2,0>(amp, Gs + 3*4, w1 ^ w2 ^ w3);    // m16 {15,16}: Rk=z17^z18^z19
    // Xd: K -> {z14,z15}; w0 becomes z16
    #pragma unroll
    for (int k = 0; k < 4; k++) lds[lane | ((unsigned)k << 6) | (wv << 8)] = amp[k];
    __syncthreads();
    #pragma unroll
    for (int k = 0; k < 4; k++)
        amp[k] = lds[lane | ((unsigned)(k>>1) << 6) | (w0 << 7) | ((unsigned)(k&1) << 8)
                     | (w1 << 9) | (w2 << 10) | (w3 << 11)];
    __syncthreads();
    gate_mreg<3,2,0>(amp, Gs + 4*4, wpar);            // m15 {14,15}: Rk=z16..z19
    swap_reg_lane4<1,16>(amp, lane);                  // z15<->z13(l4): K={z14,z13}
    gate_mreg<3,1,0>(amp, Gs + 5*4, l4 ^ wpar);       // m14 {13,14}: Rk=z15(l4)^wpar
    swap_reg_lane4<0,8>(amp, lane);                   // z14<->z12(l3): K={z12,z13}
    gate_mreg<3,2,0>(amp, Gs + 6*4, l3 ^ l4 ^ wpar);  // m13 {12,13}
    swap_reg_lane4<1,32>(amp, lane);                  // z13<->z11(l5): K={z12,z11}
    gate_mreg<3,1,0>(amp, Gs + 7*4, l5 ^ l3 ^ l4 ^ wpar);  // m12 {11,12}
}

// ---- P1: R8 stageA<0> verbatim. L1 product (perm folded) + plain L2 b0..11. ----
__global__ __launch_bounds__(1024) void passA1(const float* __restrict__ x,
                                               float2* __restrict__ dst) {
    __shared__ float2 lds[4096];
    __shared__ float2 Gs[4*NW];
    const unsigned t = threadIdx.x;
    prep_Gs(x, Gs, t);
    __syncthreads();
    const unsigned lane = t & 63u, wv = t >> 6;
    const unsigned w0 = wv & 1u, w1 = (wv >> 1) & 1u, w2 = (wv >> 2) & 1u, w3 = wv >> 3;
    const unsigned H   = blockIdx.x;
    const unsigned Hp  = H ^ (H >> 1);
    const unsigned inj = (H & 1u) << 11;
    const unsigned lb  = (wv << 8) | (lane << 2);
    const unsigned gb  = (lb ^ (lb >> 1)) ^ inj;

    float2 amp[4];
    {
        float2 P = make_float2(1.0f, 0.0f);
        #pragma unroll
        for (int b = 12; b <= 19; b++)
            P = cmul(P, Gs[(19-b)*4 + (int)((Hp >> (b-12)) & 1u)*2]);
        #pragma unroll
        for (int b = 2; b <= 11; b++)
            P = cmul(P, Gs[(19-b)*4 + (int)((gb >> b) & 1u)*2]);
        float2 T[4];
        #pragma unroll
        for (int j = 0; j < 4; j++)
            T[j] = cmul(P, cmul(Gs[19*4 + (j&1)*2], Gs[18*4 + ((j>>1)&1)*2]));
        bool s2 = (gb & 2u) != 0u;
        amp[0] = s2 ? T[2] : T[0];
        amp[1] = s2 ? T[3] : T[1];
        amp[2] = s2 ? T[1] : T[3];
        amp[3] = s2 ? T[0] : T[2];
    }
    gate_regbit<0>(amp, Gs + 19*4);
    gate_regbit<1>(amp, Gs + 18*4);
    swap_reg_lane4<0,1>(amp, lane);
    swap_reg_lane4<1,2>(amp, lane);
    gate_regbit<0>(amp, Gs + 17*4);
    gate_regbit<1>(amp, Gs + 16*4);
    swap_reg_lane4<0,4>(amp, lane);
    swap_reg_lane4<1,8>(amp, lane);
    gate_regbit<0>(amp, Gs + 15*4);
    gate_regbit<1>(amp, Gs + 14*4);
    swap_reg_lane4<0,16>(amp, lane);
    swap_reg_lane4<1,32>(amp, lane);
    gate_regbit<0>(amp, Gs + 13*4);
    gate_regbit<1>(amp, Gs + 12*4);
    #pragma unroll
    for (int k = 0; k < 4; k++) lds[lane | ((unsigned)k << 6) | (wv << 8)] = amp[k];
    __syncthreads();
    #pragma unroll
    for (int k = 0; k < 4; k++)
        amp[k] = lds[lane | (w0 << 6) | (w1 << 7) | ((unsigned)k << 8) | (w2 << 10) | (w3 << 11)];
    gate_regbit<0>(amp, Gs + 11*4);
    gate_regbit<1>(amp, Gs + 10*4);
    __syncthreads();
    #pragma unroll
    for (int k = 0; k < 4; k++) lds[lane | ((unsigned)k << 6) | (wv << 8)] = amp[k];
    __syncthreads();
    #pragma unroll
    for (int k = 0; k < 4; k++)
        amp[k] = lds[lane | (w2 << 6) | (w3 << 7) | (w0 << 8) | (w1 << 9) | ((unsigned)k << 10)];
    gate_regbit<0>(amp, Gs + 9*4);
    gate_regbit<1>(amp, Gs + 8*4);
    float2* d = dst + ((size_t)H << 12);
    #pragma unroll
    for (int k = 0; k < 4; k++)
        d[lane | (w0 << 6) | (w1 << 7) | (w2 << 8) | (w3 << 9) | ((unsigned)k << 10)] = amp[k];
}

// ---- P2: plain L2 b12..19 THEN masked L3 b12..19. In-place, block bb=z3..10. ----
// Load map: K={z12,z13}, l012=z0..2, l3=z14, l4=z15, l5=z11, wv={z16,z17,z18,z19}.
__global__ __launch_bounds__(1024) void passB2(const float* __restrict__ x,
                                               float2* __restrict__ st) {
    __shared__ float2 lds[4096];
    __shared__ float2 Gs[4*NW];
    const unsigned t = threadIdx.x, lane = t & 63u, wv = t >> 6;
    const unsigned w0 = wv & 1u, w1 = (wv >> 1) & 1u, w2 = (wv >> 2) & 1u, w3 = wv >> 3;
    const unsigned bb = blockIdx.x;
    const unsigned l012 = lane & 7u;
    const unsigned l3 = (lane >> 3) & 1u, l4 = (lane >> 4) & 1u, l5 = lane >> 5;

    float2 amp[4];
    const unsigned base = l012 | (bb << 3) | (l5 << 11) | (l3 << 14) | (l4 << 15)
                        | (w0 << 16) | (w1 << 17) | (w2 << 18) | (w3 << 19);
    #pragma unroll
    for (int k = 0; k < 4; k++)
        amp[k] = st[base | ((unsigned)(k & 1) << 12) | ((unsigned)(k >> 1) << 13)];
    prep_Gs(x, Gs, t);
    __syncthreads();

    // ---- plain phase: L2 b12..19 ----
    gate_regbit<0>(amp, Gs + 7*4);    // p12
    gate_regbit<1>(amp, Gs + 6*4);    // p13
    swap_reg_lane4<0,8>(amp, lane);   // z12<->z14: K={z14,z13}, l3=z12
    gate_regbit<0>(amp, Gs + 5*4);    // p14
    swap_reg_lane4<1,16>(amp, lane);  // z13<->z15: K={z14,z15}, l4=z13
    gate_regbit<1>(amp, Gs + 4*4);    // p15
    // X1: K {z14,z15} -> {z16,z17}; waves become {z14,z15,z18,z19}
    #pragma unroll
    for (int k = 0; k < 4; k++) lds[lane | ((unsigned)k << 6) | (wv << 8)] = amp[k];
    __syncthreads();
    #pragma unroll
    for (int k = 0; k < 4; k++)
        amp[k] = lds[lane | (w0 << 6) | (w1 << 7) | ((unsigned)(k&1) << 8)
                     | ((unsigned)(k>>1) << 9) | (w2 << 10) | (w3 << 11)];
    __syncthreads();
    gate_regbit<0>(amp, Gs + 3*4);    // p16
    gate_regbit<1>(amp, Gs + 2*4);    // p17
    // X2: K -> {z18,z19}; waves become {z14,z15,z16,z17}
    #pragma unroll
    for (int k = 0; k < 4; k++) lds[lane | ((unsigned)k << 6) | (wv << 8)] = amp[k];
    __syncthreads();
    #pragma unroll
    for (int k = 0; k < 4; k++)
        amp[k] = lds[lane | (w2 << 6) | (w3 << 7) | (w0 << 8) | (w1 << 9)
                     | ((unsigned)(k&1) << 10) | ((unsigned)(k>>1) << 11)];
    __syncthreads();
    gate_regbit<0>(amp, Gs + 1*4);    // p18
    gate_regbit<1>(amp, Gs + 0*4);    // p19  -> ALL plain L2 done
    // entry map for masked_high: K={z18,z19}, l3=z12, l4=z13, l5=z11, w={z14..z17} ✓

    // ---- masked phase: L3 b12..19 ----
    masked_high(amp, lds, Gs, lane, wv);

    // store (exit map: k0=z12, k1=z11; l3=z14, l4=z15, l5=z13; w0=z16..w3=z19)
    const unsigned sb = l012 | (bb << 3) | (l5 << 13) | (l3 << 14) | (l4 << 15)
                      | (w0 << 16) | (w1 << 17) | (w2 << 18) | (w3 << 19);
    #pragma unroll
    for (int k = 0; k < 4; k++)
        st[sb | ((unsigned)(k >> 1) << 11) | ((unsigned)(k & 1) << 12)] = amp[k];
}

// ---- P3: gray-fold read + plain L3 b0..11 [R8 walk] THEN masked L4 b0..11. ----
__global__ __launch_bounds__(1024) void passA3(const float* __restrict__ x,
                                               const float2* __restrict__ src,
                                               float2* __restrict__ dst) {
    __shared__ float2 lds[4096];
    __shared__ float2 Gs[4*NW];
    const unsigned t = threadIdx.x, lane = t & 63u, wv = t >> 6;
    const unsigned w0 = wv & 1u, w1 = (wv >> 1) & 1u, w2 = (wv >> 2) & 1u, w3 = wv >> 3;
    const unsigned H   = blockIdx.x;
    const unsigned Hp  = H ^ (H >> 1);
    const unsigned inj = (H & 1u) << 11;
    const unsigned lb  = (wv << 8) | (lane << 2);
    const unsigned gb  = (lb ^ (lb >> 1)) ^ inj;

    float4 q0, q1;                                     // loads before prep
    {
        const float4* q = (const float4*)(src + ((size_t)Hp << 12) + (gb & ~3u));
        q0 = q[0]; q1 = q[1];
    }
    prep_Gs(x, Gs, t);
    __syncthreads();

    float2 amp[4];                                     // R8-verified gray unpack
    {
        float2 e0 = make_float2(q0.x,q0.y), e1 = make_float2(q0.z,q0.w);
        float2 e2 = make_float2(q1.x,q1.y), e3 = make_float2(q1.z,q1.w);
        bool s2 = (gb & 2u) != 0u;
        amp[0] = s2 ? e2 : e0;
        amp[1] = s2 ? e3 : e1;
        amp[2] = s2 ? e1 : e3;
        amp[3] = s2 ? e0 : e2;
    }
    // ---- plain phase: L3 b0..11 (R8 stageA walk verbatim) ----
    gate_regbit<0>(amp, Gs + 19*4);
    gate_regbit<1>(amp, Gs + 18*4);
    swap_reg_lane4<0,1>(amp, lane);
    swap_reg_lane4<1,2>(amp, lane);
    gate_regbit<0>(amp, Gs + 17*4);
    gate_regbit<1>(amp, Gs + 16*4);
    swap_reg_lane4<0,4>(amp, lane);
    swap_reg_lane4<1,8>(amp, lane);
    gate_regbit<0>(amp, Gs + 15*4);
    gate_regbit<1>(amp, Gs + 14*4);
    swap_reg_lane4<0,16>(amp, lane);
    swap_reg_lane4<1,32>(amp, lane);
    gate_regbit<0>(amp, Gs + 13*4);
    gate_regbit<1>(amp, Gs + 12*4);
    #pragma unroll
    for (int k = 0; k < 4; k++) lds[lane | ((unsigned)k << 6) | (wv << 8)] = amp[k];
    __syncthreads();
    #pragma unroll
    for (int k = 0; k < 4; k++)
        amp[k] = lds[lane | (w0 << 6) | (w1 << 7) | ((unsigned)k << 8) | (w2 << 10) | (w3 << 11)];
    gate_regbit<0>(amp, Gs + 11*4);
    gate_regbit<1>(amp, Gs + 10*4);
    __syncthreads();
    #pragma unroll
    for (int k = 0; k < 4; k++) lds[lane | ((unsigned)k << 6) | (wv << 8)] = amp[k];
    __syncthreads();
    #pragma unroll
    for (int k = 0; k < 4; k++)
        amp[k] = lds[lane | (w2 << 6) | (w3 << 7) | (w0 << 8) | (w1 << 9) | ((unsigned)k << 10)];
    gate_regbit<0>(amp, Gs + 9*4);
    gate_regbit<1>(amp, Gs + 8*4);
    // plain map now: l0..5 = z0..5; w0=z6,w1=z7,w2=z8,w3=z9; K={z10,z11}. ALL L3 done.
    __syncthreads();

    // ---- masked phase: L4 b0..11, ascending walk ----
    const unsigned PH = (unsigned)__popc(H) & 1u;
    const unsigned wpar = w0 ^ w1 ^ w2 ^ w3;           // z6^z7^z8^z9
    const unsigned lpar = (unsigned)__popc(lane) & 1u;
    const unsigned l0v = lane & 1u, l1v = (lane >> 1) & 1u;
    const unsigned l3v = (lane >> 3) & 1u, l4v = (lane >> 4) & 1u, l5v = lane >> 5;
    swap_reg_lane4<0,1>(amp, lane);                    // z10<->z0: K={z0,z11}, l0=z10
    swap_reg_lane4<1,2>(amp, lane);                    // z11<->z1: K={z0,z1}, l1=z11
    gate_mreg<1,1,2>(amp, Gs + 19*4, lpar ^ wpar ^ PH);            // m0 {0}
    gate_mreg<3,2,0>(amp, Gs + 18*4, lpar ^ wpar ^ PH);            // m1 {0,1}
    swap_reg_lane4<0,4>(amp, lane);                    // z0<->z2: K={z2,z1}, l2=z0
    gate_mreg<3,1,0>(amp, Gs + 17*4, l3v^l4v^l5v ^ l0v^l1v ^ wpar ^ PH);  // m2 {1,2}
    swap_reg_lane4<1,8>(amp, lane);                    // z1<->z3: K={z2,z3}, l3=z1
    gate_mreg<3,2,0>(amp, Gs + 16*4, l4v^l5v ^ l0v^l1v ^ wpar ^ PH);      // m3 {2,3}
    swap_reg_lane4<0,16>(amp, lane);                   // z2<->z4: K={z4,z3}, l4=z2
    gate_mreg<3,1,0>(amp, Gs + 15*4, l5v ^ l0v^l1v ^ wpar ^ PH);          // m4 {3,4}
    swap_reg_lane4<1,32>(amp, lane);                   // z3<->z5: K={z4,z5}, l5=z3
    gate_mreg<3,2,0>(amp, Gs + 14*4, l0v^l1v ^ wpar ^ PH);                // m5 {4,5}
    // lanes now: l0=z10, l1=z11, l2=z0, l3=z1, l4=z2, l5=z3
    // X1'': K -> {z5,z6}; waves {z4,z7,z8,z9}
    #pragma unroll
    for (int k = 0; k < 4; k++) lds[lane | ((unsigned)k << 6) | (wv << 8)] = amp[k];
    __syncthreads();
    #pragma unroll
    for (int k = 0; k < 4; k++)
        amp[k] = lds[lane | (w0 << 6) | ((unsigned)(k&1) << 7) | ((unsigned)(k>>1) << 8)
                     | (w1 << 9) | (w2 << 10) | (w3 << 11)];
    __syncthreads();
    gate_mreg<3,2,0>(amp, Gs + 13*4, w1^w2^w3 ^ l0v^l1v ^ PH);     // m6 {5,6}
    // X2'': K -> {z6,z7}; waves {z4,z5,z8,z9}
    #pragma unroll
    for (int k = 0; k < 4; k++) lds[lane | ((unsigned)k << 6) | (wv << 8)] = amp[k];
    __syncthreads();
    #pragma unroll
    for (int k = 0; k < 4; k++)
        amp[k] = lds[lane | (w1 << 6) | ((unsigned)(k&1) << 7) | (w0 << 8)
                     | ((unsigned)(k>>1) << 9) | (w2 << 10) | (w3 << 11)];
    __syncthreads();
    gate_mreg<3,2,0>(amp, Gs + 12*4, w2^w3 ^ l0v^l1v ^ PH);        // m7 {6,7}
    // X3'': K -> {z7,z8}; waves {z4,z5,z6,z9}
    #pragma unroll
    for (int k = 0; k < 4; k++) lds[lane | ((unsigned)k << 6) | (wv << 8)] = amp[k];
    __syncthreads();
    #pragma unroll
    for (int k = 0; k < 4; k++)
        amp[k] = lds[lane | (w2 << 6) | ((unsigned)(k&1) << 7) | (w0 << 8)
                     | (w1 << 9) | ((unsigned)(k>>1) << 10) | (w3 << 11)];
    __syncthreads();
    gate_mreg<3,2,0>(amp, Gs + 11*4, w3 ^ l0v^l1v ^ PH);           // m8 {7,8}
    // X4'': K -> {z8,z9}; waves {z4,z5,z6,z7}
    #pragma unroll
    for (int k = 0; k < 4; k++) lds[lane | ((unsigned)k << 6) | (wv << 8)] = amp[k];
    __syncthreads();
    #pragma unroll
    for (int k = 0; k < 4; k++)
        amp[k] = lds[lane | (w3 << 6) | ((unsigned)(k&1) << 7) | (w0 << 8)
                     | (w1 << 9) | (w2 << 10) | ((unsigned)(k>>1) << 11)];
    gate_mreg<3,2,0>(amp, Gs + 10*4, l0v^l1v ^ PH);                // m9 {8,9}
    swap_reg_lane4<0,1>(amp, lane);                    // z8<->z10(l0): K={z10,z9}, l0=z8
    gate_mreg<3,1,0>(amp, Gs + 9*4, l1v ^ PH);                     // m10 {9,10}
    swap_reg_lane4<1,2>(amp, lane);                    // z9<->z11(l1): K={z10,z11}, l1=z9
    gate_mreg<3,2,0>(amp, Gs + 8*4, PH);                           // m11 {10,11}
    // store F2 logical: l2..l5=z0..z3, w0..w3=z4..z7, l0=z8, l1=z9, K={z10,z11}
    const unsigned sb = ((lane >> 2) & 1u) | (l3v << 1) | (l4v << 2) | (l5v << 3)
                      | (w0 << 4) | (w1 << 5) | (w2 << 6) | (w3 << 7)
                      | (l0v << 8) | (l1v << 9);
    float2* d = dst + ((size_t)H << 12);
    #pragma unroll
    for (int k = 0; k < 4; k++)
        d[sb | ((unsigned)(k & 1) << 10) | ((unsigned)(k >> 1) << 11)] = amp[k];
}

// ---- P4: masked L4 b12..19 + expectation (2 perms pending). Block bb=z3..10. ----
// Load map (matches masked_high entry): K={z18,z19}, l3=z12, l4=z13, l5=z11,
// w0=z14, w1=z15, w2=z16, w3=z17.
__global__ __launch_bounds__(1024) void passB4(const float* __restrict__ x,
                                               const float2* __restrict__ st,
                                               float* __restrict__ partial) {
    __shared__ float2 lds[4096];
    __shared__ float2 Gs[4*NW];
    const unsigned t = threadIdx.x, lane = t & 63u, wv = t >> 6;
    const unsigned w0 = wv & 1u, w1 = (wv >> 1) & 1u, w2 = (wv >> 2) & 1u, w3 = wv >> 3;
    const unsigned bb = blockIdx.x;
    const unsigned l012 = lane & 7u;
    const unsigned l3 = (lane >> 3) & 1u, l4 = (lane >> 4) & 1u, l5 = lane >> 5;

    float2 amp[4];
    const unsigned base = l012 | (bb << 3) | (l5 << 11) | (l3 << 12) | (l4 << 13)
                        | (w0 << 14) | (w1 << 15) | (w2 << 16) | (w3 << 17);
    #pragma unroll
    for (int k = 0; k < 4; k++)
        amp[k] = st[base | ((unsigned)(k & 1) << 18) | ((unsigned)(k >> 1) << 19)];
    prep_Gs(x, Gs, t);
    __syncthreads();

    masked_high(amp, lds, Gs, lane, wv);
    // exit map: k0=z12, k1=z11; l3=z14, l4=z15, l5=z13; w0=z16..w3=z19

    // expectation: sign(wire w) = invgray^2(z) bit b=19-w = pfx2(z)_b.
    // z11 (k1) affects odd b<=11; z12 (k0) affects even b<=12; b>=13 k-independent.
    float p[4];
    #pragma unroll
    for (int k = 0; k < 4; k++) p[k] = amp[k].x*amp[k].x + amp[k].y*amp[k].y;
    const float T = p[0] + p[1] + p[2] + p[3];
    const float E = (p[0] + p[2]) - (p[1] + p[3]);     // flip with k0 (z12)
    const float O = (p[0] + p[1]) - (p[2] + p[3]);     // flip with k1 (z11)
    const unsigned zbase = l012 | (bb << 3) | (l5 << 13) | (l3 << 14) | (l4 << 15)
                         | (w0 << 16) | (w1 << 17) | (w2 << 18) | (w3 << 19);
    const unsigned t2 = pfx2(zbase);
    float acc[NW];
    #pragma unroll
    for (int w = 0; w < NW; w++) {
        int b = 19 - w;
        float v = (b >= 13) ? T : ((b & 1) ? O : E);
        acc[w] = ((t2 >> b) & 1u) ? -v : v;
    }
    __syncthreads();                  // reuse lds for reduction
    float* red = (float*)lds;
    #pragma unroll
    for (int w = 0; w < NW; w++) {
        float s = acc[w];
        #pragma unroll
        for (int off = 32; off; off >>= 1) s += __shfl_down(s, off, 64);
        if (lane == 0) red[wv*NW + w] = s;
    }
    __syncthreads();
    if (t < NW) {
        float s = 0.0f;
        #pragma unroll
        for (int v16 = 0; v16 < 16; v16++) s += red[v16*NW + (int)t];
        partial[bb*NW + t] = s;
    }
}

__global__ __launch_bounds__(256) void reduce_out(const float* __restrict__ partial,
                                                  float* __restrict__ out) {
    __shared__ float red[4*NW];
    unsigned t = threadIdx.x;
    float vals[NW];
    #pragma unroll
    for (int w = 0; w < NW; w++) vals[w] = partial[t*NW + w];
    #pragma unroll
    for (int w = 0; w < NW; w++) {
        float v = vals[w];
        #pragma unroll
        for (int off = 32; off; off >>= 1) v += __shfl_down(v, off, 64);
        if ((t & 63u) == 0u) red[(t >> 6)*NW + w] = v;
    }
    __syncthreads();
    if (t < NW) out[t] = red[t] + red[NW+t] + red[2*NW+t] + red[3*NW+t];
}

extern "C" void kernel_launch(void* const* d_in, const int* in_sizes, int n_in,
                              void* d_out, int out_size, void* d_ws, size_t ws_size,
                              hipStream_t stream) {
    (void)in_sizes; (void)n_in; (void)out_size; (void)ws_size;
    const float* x = (const float*)d_in[0];
    float* out = (float*)d_out;

    char* ws = (char*)d_ws;
    float*  partial = (float*)(ws + 1024);                        // 20 KB
    float2* buf0    = (float2*)(ws + 65536);                      // 8 MB (F1)
    float2* buf1    = (float2*)(ws + 65536 + (size_t)(8u << 20)); // 8 MB (F2)

    passA1<<<256, 1024, 0, stream>>>(x, buf0);            // L1 + L2 b0..11
    passB2<<<256, 1024, 0, stream>>>(x, buf0);            // L2 b12..19 + mL3 b12..19
    passA3<<<256, 1024, 0, stream>>>(x, buf0, buf1);      // fold + L3 b0..11 + mL4 b0..11
    passB4<<<256, 1024, 0, stream>>>(x, buf1, partial);   // mL4 b12..19 + expectation
    reduce_out<<<1, 256, 0, stream>>>(partial, out);
}

// Round 13
// 73.372 us; speedup vs baseline: 1.0917x; 1.0917x over previous
//
#include <hip/hip_runtime.h>

// 20-qubit feature map, 4 layers (RX·RY per wire + CNOT chain), <Z_i> outputs.
// wire w <-> bit b=19-w. CNOT chain == gray perm: new[y]=old[y^(y>>1)], folded
// into the next A read (MODE1) or final expectation (FUSE). Layer 1 on |0..0> =
// product state in-register (MODE0).
// R13 = R8's 6-pass skeleton with SINGLE-LDS-trip walks (R8 used 2 trips/pass;
// parking the last 2 bits in lane slots l4,l5 instead of wave slots lets
// butterflies finish the walk). Barriers/pass: 5 -> 3. Masked fusion (R12) and
// any device-scope rendezvous (R7/R9) are proven losers; dispatch boundaries
// stay as the cross-XCD barrier.
// stageA maps: load/store logical, z0..3 in lanes l0..3 (128B runs x4).
//   pre-trip:  K={z0,z1}->..walk..-> K={z6,z7}, l0..5=z0..5, w=z8..11
//   trip read: K={z8,z9}, l4'=z10, l5'=z11, w'={z4,z5,z6,z7}
//   post:      b8,b9; bf z8<->z10; b10; bf z9<->z11; b11
// stageB maps: block bb=z4..11; l0..3=z0..3; K={z12,z13}, l4=z14, l5=z15,
//   w={z16..19}; after b12..15 trip to K={z16,z17}, l4'=z18, l5'=z19,
//   w'={z12..15}; b16..b19 via 2 butterflies.

#define NW 20

__device__ __forceinline__ float2 cmul(float2 a, float2 b) {
    return make_float2(a.x*b.x - a.y*b.y, a.x*b.y + a.y*b.x);
}

__device__ __forceinline__ void apply_gate(float2& a0, float2& a1,
                                           float2 u00, float2 u01,
                                           float2 u10, float2 u11) {
    float2 b0, b1;
    b0.x = u00.x*a0.x - u00.y*a0.y + u01.x*a1.x - u01.y*a1.y;
    b0.y = u00.x*a0.y + u00.y*a0.x + u01.x*a1.y + u01.y*a1.x;
    b1.x = u10.x*a0.x - u10.y*a0.y + u11.x*a1.x - u11.y*a1.y;
    b1.y = u10.x*a0.y + u10.y*a0.x + u11.x*a1.y + u11.y*a1.x;
    a0 = b0; a1 = b1;
}

__device__ __forceinline__ float2 shflx(float2 v, int m) {
    float2 r;
    r.x = __shfl_xor(v.x, m, 64);
    r.y = __shfl_xor(v.y, m, 64);
    return r;
}

// suffix-XOR: bit b of result = XOR_{j>=b} x_j
__device__ __forceinline__ unsigned sfx(unsigned x) {
    x ^= x >> 1; x ^= x >> 2; x ^= x >> 4; x ^= x >> 8; x ^= x >> 16; return x;
}

template<int A>
__device__ __forceinline__ void gate_regbit(float2 (&amp)[4], const float2* Gw) {
    float2 u00 = Gw[0], u01 = Gw[1], u10 = Gw[2], u11 = Gw[3];
    #pragma unroll
    for (int r = 0; r < 4; r++)
        if (!(r & (1 << A)))
            apply_gate(amp[r], amp[r | (1 << A)], u00, u01, u10, u11);
}

// butterfly: swap reg-bit A content with lane-bit LM content [R4-verified]
template<int A, int LM>
__device__ __forceinline__ void swap_reg_lane4(float2 (&amp)[4], unsigned lane) {
    bool hb = (lane & (unsigned)LM) != 0u;
    #pragma unroll
    for (int r = 0; r < 4; r++) {
        if (!(r & (1 << A))) {
            float2 lo = amp[r], hi = amp[r | (1 << A)];
            float2 xs = hb ? lo : hi;
            float2 ys = shflx(xs, LM);
            amp[r]            = hb ? ys : lo;
            amp[r | (1 << A)] = hb ? hi : ys;
        }
    }
}

// U = RY(x)*RX(x), half-angle. G[w*4 + r*2 + c] = U^w[r][c].
__device__ __forceinline__ void prep_Gs(const float* __restrict__ x, float2* Gs,
                                        unsigned t) {
    if (t < NW) {
        float h = 0.5f * x[t];
        float c = cosf(h), s = sinf(h);
        float cc = c*c, ss = s*s, cs = c*s;
        Gs[t*4+0] = make_float2(cc,  ss);
        Gs[t*4+1] = make_float2(-cs, -cs);
        Gs[t*4+2] = make_float2(cs,  -cs);
        Gs[t*4+3] = make_float2(cc,  -ss);
    }
}

// Stage A: gates on bits 0..11. Block = logical high byte H = z12..19.
// MODE 0: product state (layer-1 folded). MODE 1: gray-fold read from src.
template<int MODE>
__global__ __launch_bounds__(1024) void stageA(const float* __restrict__ x,
                                               const float2* __restrict__ src,
                                               float2* __restrict__ dst) {
    __shared__ float2 lds[4096];
    __shared__ float2 Gs[4*NW];
    const unsigned t = threadIdx.x;
    const unsigned lane = t & 63u, wv = t >> 6;
    const unsigned w0 = wv & 1u, w1 = (wv >> 1) & 1u, w2 = (wv >> 2) & 1u, w3 = wv >> 3;
    const unsigned l4v = (lane >> 4) & 1u, l5v = lane >> 5;
    const unsigned H   = blockIdx.x;
    const unsigned Hp  = H ^ (H >> 1);
    const unsigned inj = (H & 1u) << 11;
    const unsigned lb  = (wv << 8) | (lane << 2);         // logical low-12 base
    const unsigned gb  = (lb ^ (lb >> 1)) ^ inj;          // gray12 ^ inj

    float4 q0, q1;
    if (MODE == 1) {                                      // loads before prep
        const float4* q = (const float4*)(src + ((size_t)Hp << 12) + (gb & ~3u));
        q0 = q[0]; q1 = q[1];
    }
    prep_Gs(x, Gs, t);
    __syncthreads();

    float2 amp[4];                  // map: K={z0,z1}, l0..5=z2..7, w=z8..11
    if (MODE == 1) {
        float2 e0 = make_float2(q0.x,q0.y), e1 = make_float2(q0.z,q0.w);
        float2 e2 = make_float2(q1.x,q1.y), e3 = make_float2(q1.z,q1.w);
        bool s2 = (gb & 2u) != 0u;   // amp[k] = e[(gb&3) ^ gray2(k)]
        amp[0] = s2 ? e2 : e0;
        amp[1] = s2 ? e3 : e1;
        amp[2] = s2 ? e1 : e3;
        amp[3] = s2 ? e0 : e2;
    } else {
        float2 P = make_float2(1.0f, 0.0f);
        #pragma unroll
        for (int b = 12; b <= 19; b++)
            P = cmul(P, Gs[(19-b)*4 + (int)((Hp >> (b-12)) & 1u)*2]);
        #pragma unroll
        for (int b = 2; b <= 11; b++)
            P = cmul(P, Gs[(19-b)*4 + (int)((gb >> b) & 1u)*2]);
        float2 T[4];
        #pragma unroll
        for (int j = 0; j < 4; j++)
            T[j] = cmul(P, cmul(Gs[19*4 + (j&1)*2], Gs[18*4 + ((j>>1)&1)*2]));
        bool s2 = (gb & 2u) != 0u;
        amp[0] = s2 ? T[2] : T[0];
        amp[1] = s2 ? T[3] : T[1];
        amp[2] = s2 ? T[1] : T[3];
        amp[3] = s2 ? T[0] : T[2];
    }

    // plain walk b0..b7 (R8 verbatim)
    gate_regbit<0>(amp, Gs + 19*4);   // b0
    gate_regbit<1>(amp, Gs + 18*4);   // b1
    swap_reg_lane4<0,1>(amp, lane);   // z0<->z2
    swap_reg_lane4<1,2>(amp, lane);   // z1<->z3
    gate_regbit<0>(amp, Gs + 17*4);   // b2
    gate_regbit<1>(amp, Gs + 16*4);   // b3
    swap_reg_lane4<0,4>(amp, lane);
    swap_reg_lane4<1,8>(amp, lane);
    gate_regbit<0>(amp, Gs + 15*4);   // b4
    gate_regbit<1>(amp, Gs + 14*4);   // b5
    swap_reg_lane4<0,16>(amp, lane);
    swap_reg_lane4<1,32>(amp, lane);
    gate_regbit<0>(amp, Gs + 13*4);   // b6
    gate_regbit<1>(amp, Gs + 12*4);   // b7
    // map: l0..5=z0..5, K={z6,z7}, w=z8..11
    // SINGLE trip: a0..5=z0..5, a6=z6, a7=z7, a8..11=z8..11
    #pragma unroll
    for (int k = 0; k < 4; k++) lds[lane | ((unsigned)k << 6) | (wv << 8)] = amp[k];
    __syncthreads();
    // read: K={z8,z9}, l4'=z10, l5'=z11, w'={z4,z5,z6,z7}; l0..3 keep z0..3
    #pragma unroll
    for (int k = 0; k < 4; k++)
        amp[k] = lds[(lane & 15u) | (w0 << 4) | (w1 << 5) | (w2 << 6) | (w3 << 7)
                     | ((unsigned)(k & 1) << 8) | ((unsigned)(k >> 1) << 9)
                     | (l4v << 10) | (l5v << 11)];
    gate_regbit<0>(amp, Gs + 11*4);   // b8
    gate_regbit<1>(amp, Gs + 10*4);   // b9
    swap_reg_lane4<0,16>(amp, lane);  // z8<->z10: K={z10,z9}, l4=z8
    gate_regbit<0>(amp, Gs + 9*4);    // b10
    swap_reg_lane4<1,32>(amp, lane);  // z9<->z11: K={z10,z11}, l5=z9
    gate_regbit<1>(amp, Gs + 8*4);    // b11
    // store logical: l0..3=z0..3, w=z4..7, l4=z8, l5=z9, K={z10,z11}
    float2* d = dst + ((size_t)H << 12);
    #pragma unroll
    for (int k = 0; k < 4; k++)
        d[(lane & 15u) | (w0 << 4) | (w1 << 5) | (w2 << 6) | (w3 << 7)
          | (l4v << 8) | (l5v << 9)
          | ((unsigned)(k & 1) << 10) | ((unsigned)(k >> 1) << 11)] = amp[k];
}

// Stage B: gates on bits 12..19; in-place; block bb = z4..11; l0..3 = z0..3.
// FUSE=1: fold last gray perm + expectation partials.
template<int FUSE>
__global__ __launch_bounds__(1024) void stageB(const float* __restrict__ x,
                                               float2* __restrict__ st,
                                               float* __restrict__ partial) {
    __shared__ float2 lds[4096];
    __shared__ float2 Gs[4*NW];
    const unsigned t = threadIdx.x;
    const unsigned lane = t & 63u, wv = t >> 6;
    const unsigned w0 = wv & 1u, w1 = (wv >> 1) & 1u, w2 = (wv >> 2) & 1u, w3 = wv >> 3;
    const unsigned m = lane & 15u, l4v = (lane >> 4) & 1u, l5v = lane >> 5;
    const unsigned bb = blockIdx.x;

    // load (before prep): K={z12,z13}, l4=z14, l5=z15, w={z16..19}
    float2 amp[4];
    const unsigned lbase = m | (bb << 4) | (l4v << 14) | (l5v << 15)
                         | (w0 << 16) | (w1 << 17) | (w2 << 18) | (w3 << 19);
    #pragma unroll
    for (int k = 0; k < 4; k++)
        amp[k] = st[lbase | ((unsigned)(k & 1) << 12) | ((unsigned)(k >> 1) << 13)];
    prep_Gs(x, Gs, t);
    __syncthreads();

    gate_regbit<0>(amp, Gs + 7*4);    // b12
    gate_regbit<1>(amp, Gs + 6*4);    // b13
    swap_reg_lane4<0,16>(amp, lane);  // z12<->z14: K={z14,z13}, l4=z12
    swap_reg_lane4<1,32>(amp, lane);  // z13<->z15: K={z14,z15}, l5=z13
    gate_regbit<0>(amp, Gs + 5*4);    // b14
    gate_regbit<1>(amp, Gs + 4*4);    // b15
    // SINGLE trip: a0..3=z0..3, a4=z12, a5=z13, a6=z14, a7=z15, a8..11=z16..19
    #pragma unroll
    for (int k = 0; k < 4; k++) lds[lane | ((unsigned)k << 6) | (wv << 8)] = amp[k];
    __syncthreads();
    // read: K={z16,z17}, l4'=z18, l5'=z19, w'={z12,z13,z14,z15}
    #pragma unroll
    for (int k = 0; k < 4; k++)
        amp[k] = lds[(lane & 15u) | (w0 << 4) | (w1 << 5) | (w2 << 6) | (w3 << 7)
                     | ((unsigned)(k & 1) << 8) | ((unsigned)(k >> 1) << 9)
                     | (l4v << 10) | (l5v << 11)];
    gate_regbit<0>(amp, Gs + 3*4);    // b16
    gate_regbit<1>(amp, Gs + 2*4);    // b17
    swap_reg_lane4<0,16>(amp, lane);  // z16<->z18: K={z18,z17}, l4=z16
    gate_regbit<0>(amp, Gs + 1*4);    // b18
    swap_reg_lane4<1,32>(amp, lane);  // z17<->z19: K={z18,z19}, l5=z17
    gate_regbit<1>(amp, Gs + 0*4);    // b19
    // final map: l0..3=z0..3, w={z12..15}, l4=z16, l5=z17, K={z18,z19}

    if (!FUSE) {
        #pragma unroll
        for (int k = 0; k < 4; k++)
            st[m | (bb << 4) | (w0 << 12) | (w1 << 13) | (w2 << 14) | (w3 << 15)
               | (l4v << 16) | (l5v << 17)
               | ((unsigned)(k & 1) << 18) | ((unsigned)(k >> 1) << 19)] = amp[k];
    } else {
        // y = invgray(Y); k0=Y18, k1=Y19 (same k-convention as R8 -> same S19,D).
        float p[4];
        #pragma unroll
        for (int k = 0; k < 4; k++) p[k] = amp[k].x*amp[k].x + amp[k].y*amp[k].y;
        float S19 = (p[0] + p[1]) - (p[2] + p[3]);      // (-1)^{Y19}
        float D   = p[0] - p[1] - p[2] + p[3];          // (-1)^{Y18^Y19}
        unsigned v = m | (bb << 4) | (w0 << 12) | (w1 << 13) | (w2 << 14)
                   | (w3 << 15) | (l4v << 16) | (l5v << 17);   // Y bits 0..17
        unsigned cm = sfx(v);                            // cm_b = XOR_{j=b..17} Y_j
        float acc[NW];
        acc[0] = S19; acc[1] = D;
        #pragma unroll
        for (int w = 2; w < NW; w++)
            acc[w] = ((cm >> (19 - w)) & 1u) ? -D : D;

        __syncthreads();                 // LDS reads done; reuse for reduction
        float* red = (float*)lds;
        #pragma unroll
        for (int w = 0; w < NW; w++) {
            float s = acc[w];
            #pragma unroll
            for (int off = 32; off; off >>= 1) s += __shfl_down(s, off, 64);
            if (lane == 0) red[wv*NW + w] = s;
        }
        __syncthreads();
        if (t < NW) {
            float s = 0.0f;
            #pragma unroll
            for (int v16 = 0; v16 < 16; v16++) s += red[v16*NW + (int)t];
            partial[bb*NW + t] = s;
        }
    }
}

__global__ __launch_bounds__(256) void reduce_out(const float* __restrict__ partial,
                                                  float* __restrict__ out) {
    __shared__ float red[4*NW];
    unsigned t = threadIdx.x;
    float vals[NW];
    #pragma unroll
    for (int w = 0; w < NW; w++) vals[w] = partial[t*NW + w];
    #pragma unroll
    for (int w = 0; w < NW; w++) {
        float v = vals[w];
        #pragma unroll
        for (int off = 32; off; off >>= 1) v += __shfl_down(v, off, 64);
        if ((t & 63u) == 0u) red[(t >> 6)*NW + w] = v;
    }
    __syncthreads();
    if (t < NW) out[t] = red[t] + red[NW+t] + red[2*NW+t] + red[3*NW+t];
}

extern "C" void kernel_launch(void* const* d_in, const int* in_sizes, int n_in,
                              void* d_out, int out_size, void* d_ws, size_t ws_size,
                              hipStream_t stream) {
    (void)in_sizes; (void)n_in; (void)out_size; (void)ws_size;
    const float* x = (const float*)d_in[0];
    float* out = (float*)d_out;

    char* ws = (char*)d_ws;
    float*  partial = (float*)(ws + 1024);                        // 20 KB
    float2* buf0    = (float2*)(ws + 65536);                      // 8 MB
    float2* buf1    = (float2*)(ws + 65536 + (size_t)(8u << 20)); // 8 MB

    // layer 1 folded into product state; layer 2:
    stageA<0><<<256, 1024, 0, stream>>>(x, buf1 /*unused*/, buf0);
    stageB<0><<<256, 1024, 0, stream>>>(x, buf0, nullptr);
    // layer 3 (perm folded into A read):
    stageA<1><<<256, 1024, 0, stream>>>(x, buf0, buf1);
    stageB<0><<<256, 1024, 0, stream>>>(x, buf1, nullptr);
    // layer 4 (+ fused expectation, final perm folded):
    stageA<1><<<256, 1024, 0, stream>>>(x, buf1, buf0);
    stageB<1><<<256, 1024, 0, stream>>>(x, buf0, partial);
    reduce_out<<<1, 256, 0, stream>>>(partial, out);
}

// Round 14
// 67.868 us; speedup vs baseline: 1.1802x; 1.0811x over previous
//
#include <hip/hip_runtime.h>

// 20-qubit feature map, 4 layers (RX·RY per wire + CNOT chain), <Z_i> outputs.
// wire w <-> bit b=19-w. CNOT chain == gray perm: new[y]=old[y^(y>>1)], folded
// into the next A read (MODE1) or final expectation (FUSE). Layer 1 on |0..0> =
// product state in-register (MODE0).
// R14 = R8's proven 6-pass skeleton; stageA verbatim from R8 (63.7us best).
// stageB re-plumbed: z0 parked in reg k0 (never gated in B) -> thread's amp
// pairs are memory-adjacent -> 2x float4 loads + 2x float4 stores (16B/lane,
// was 8B). Single LDS trip with XOR swizzle a^=((a>>9)&7)<<3 on BOTH write and
// read (conflict-free both sides; un-swizzled single-trip was R13's regression).
// Gates ride reg k1 through 6 butterflies. Dispatch boundaries = the only cheap
// cross-XCD barrier (R7 grid.sync 29us/ea; R9 ticket+fence 78us).

#define NW 20

__device__ __forceinline__ float2 cmul(float2 a, float2 b) {
    return make_float2(a.x*b.x - a.y*b.y, a.x*b.y + a.y*b.x);
}

__device__ __forceinline__ void apply_gate(float2& a0, float2& a1,
                                           float2 u00, float2 u01,
                                           float2 u10, float2 u11) {
    float2 b0, b1;
    b0.x = u00.x*a0.x - u00.y*a0.y + u01.x*a1.x - u01.y*a1.y;
    b0.y = u00.x*a0.y + u00.y*a0.x + u01.x*a1.y + u01.y*a1.x;
    b1.x = u10.x*a0.x - u10.y*a0.y + u11.x*a1.x - u11.y*a1.y;
    b1.y = u10.x*a0.y + u10.y*a0.x + u11.x*a1.y + u11.y*a1.x;
    a0 = b0; a1 = b1;
}

__device__ __forceinline__ float2 shflx(float2 v, int m) {
    float2 r;
    r.x = __shfl_xor(v.x, m, 64);
    r.y = __shfl_xor(v.y, m, 64);
    return r;
}

// suffix-XOR: bit b of result = XOR_{j>=b} x_j
__device__ __forceinline__ unsigned sfx(unsigned x) {
    x ^= x >> 1; x ^= x >> 2; x ^= x >> 4; x ^= x >> 8; x ^= x >> 16; return x;
}

template<int A>
__device__ __forceinline__ void gate_regbit(float2 (&amp)[4], const float2* Gw) {
    float2 u00 = Gw[0], u01 = Gw[1], u10 = Gw[2], u11 = Gw[3];
    #pragma unroll
    for (int r = 0; r < 4; r++)
        if (!(r & (1 << A)))
            apply_gate(amp[r], amp[r | (1 << A)], u00, u01, u10, u11);
}

// butterfly: swap reg-bit A content with lane-bit LM content [R4-verified]
template<int A, int LM>
__device__ __forceinline__ void swap_reg_lane4(float2 (&amp)[4], unsigned lane) {
    bool hb = (lane & (unsigned)LM) != 0u;
    #pragma unroll
    for (int r = 0; r < 4; r++) {
        if (!(r & (1 << A))) {
            float2 lo = amp[r], hi = amp[r | (1 << A)];
            float2 xs = hb ? lo : hi;
            float2 ys = shflx(xs, LM);
            amp[r]            = hb ? ys : lo;
            amp[r | (1 << A)] = hb ? hi : ys;
        }
    }
}

// U = RY(x)*RX(x), half-angle. G[w*4 + r*2 + c] = U^w[r][c].
__device__ __forceinline__ void prep_Gs(const float* __restrict__ x, float2* Gs,
                                        unsigned t) {
    if (t < NW) {
        float h = 0.5f * x[t];
        float c = cosf(h), s = sinf(h);
        float cc = c*c, ss = s*s, cs = c*s;
        Gs[t*4+0] = make_float2(cc,  ss);
        Gs[t*4+1] = make_float2(-cs, -cs);
        Gs[t*4+2] = make_float2(cs,  -cs);
        Gs[t*4+3] = make_float2(cc,  -ss);
    }
}

// LDS swizzle: XOR addr bits 9..11 into bits 3..5 (same fn on write & read).
__device__ __forceinline__ unsigned swz(unsigned a) {
    return a ^ (((a >> 9) & 7u) << 3);
}

// ---- Stage A: R8 verbatim. Gates on bits 0..11. Block H = z12..19. ----
template<int MODE>
__global__ __launch_bounds__(1024) void stageA(const float* __restrict__ x,
                                               const float2* __restrict__ src,
                                               float2* __restrict__ dst) {
    __shared__ float2 lds[4096];
    __shared__ float2 Gs[4*NW];
    const unsigned t = threadIdx.x;
    const unsigned lane = t & 63u, wv = t >> 6;
    const unsigned w0 = wv & 1u, w1 = (wv >> 1) & 1u, w2 = (wv >> 2) & 1u, w3 = wv >> 3;
    const unsigned H   = blockIdx.x;
    const unsigned Hp  = H ^ (H >> 1);
    const unsigned inj = (H & 1u) << 11;
    const unsigned lb  = (wv << 8) | (lane << 2);
    const unsigned gb  = (lb ^ (lb >> 1)) ^ inj;

    float4 q0, q1;
    if (MODE == 1) {                                      // loads before prep
        const float4* q = (const float4*)(src + ((size_t)Hp << 12) + (gb & ~3u));
        q0 = q[0]; q1 = q[1];
    }
    prep_Gs(x, Gs, t);
    __syncthreads();

    float2 amp[4];
    if (MODE == 1) {
        float2 e0 = make_float2(q0.x,q0.y), e1 = make_float2(q0.z,q0.w);
        float2 e2 = make_float2(q1.x,q1.y), e3 = make_float2(q1.z,q1.w);
        bool s2 = (gb & 2u) != 0u;   // amp[k] = e[(gb&3) ^ gray2(k)]
        amp[0] = s2 ? e2 : e0;
        amp[1] = s2 ? e3 : e1;
        amp[2] = s2 ? e1 : e3;
        amp[3] = s2 ? e0 : e2;
    } else {
        float2 P = make_float2(1.0f, 0.0f);
        #pragma unroll
        for (int b = 12; b <= 19; b++)
            P = cmul(P, Gs[(19-b)*4 + (int)((Hp >> (b-12)) & 1u)*2]);
        #pragma unroll
        for (int b = 2; b <= 11; b++)
            P = cmul(P, Gs[(19-b)*4 + (int)((gb >> b) & 1u)*2]);
        float2 T[4];
        #pragma unroll
        for (int j = 0; j < 4; j++)
            T[j] = cmul(P, cmul(Gs[19*4 + (j&1)*2], Gs[18*4 + ((j>>1)&1)*2]));
        bool s2 = (gb & 2u) != 0u;
        amp[0] = s2 ? T[2] : T[0];
        amp[1] = s2 ? T[3] : T[1];
        amp[2] = s2 ? T[1] : T[3];
        amp[3] = s2 ? T[0] : T[2];
    }

    gate_regbit<0>(amp, Gs + 19*4);   // b0
    gate_regbit<1>(amp, Gs + 18*4);   // b1
    swap_reg_lane4<0,1>(amp, lane);
    swap_reg_lane4<1,2>(amp, lane);
    gate_regbit<0>(amp, Gs + 17*4);   // b2
    gate_regbit<1>(amp, Gs + 16*4);   // b3
    swap_reg_lane4<0,4>(amp, lane);
    swap_reg_lane4<1,8>(amp, lane);
    gate_regbit<0>(amp, Gs + 15*4);   // b4
    gate_regbit<1>(amp, Gs + 14*4);   // b5
    swap_reg_lane4<0,16>(amp, lane);
    swap_reg_lane4<1,32>(amp, lane);
    gate_regbit<0>(amp, Gs + 13*4);   // b6
    gate_regbit<1>(amp, Gs + 12*4);   // b7
    #pragma unroll
    for (int k = 0; k < 4; k++) lds[lane | ((unsigned)k << 6) | (wv << 8)] = amp[k];
    __syncthreads();
    #pragma unroll
    for (int k = 0; k < 4; k++)
        amp[k] = lds[lane | (w0 << 6) | (w1 << 7) | ((unsigned)k << 8) | (w2 << 10) | (w3 << 11)];
    gate_regbit<0>(amp, Gs + 11*4);   // b8
    gate_regbit<1>(amp, Gs + 10*4);   // b9
    __syncthreads();
    #pragma unroll
    for (int k = 0; k < 4; k++) lds[lane | ((unsigned)k << 6) | (wv << 8)] = amp[k];
    __syncthreads();
    #pragma unroll
    for (int k = 0; k < 4; k++)
        amp[k] = lds[lane | (w2 << 6) | (w3 << 7) | (w0 << 8) | (w1 << 9) | ((unsigned)k << 10)];
    gate_regbit<0>(amp, Gs + 9*4);    // b10
    gate_regbit<1>(amp, Gs + 8*4);    // b11
    float2* d = dst + ((size_t)H << 12);
    #pragma unroll
    for (int k = 0; k < 4; k++)
        d[lane | (w0 << 6) | (w1 << 7) | (w2 << 8) | (w3 << 9) | ((unsigned)k << 10)] = amp[k];
}

// ---- Stage B (R14): gates on bits 12..19; in-place; block bb = z4..11. ----
// Thread map: k0=z0 (ride-along), k1=z12 (walking); l0..2=z1..3;
// l3,l4,l5=z13,z14,z15; wv=z16..19. 2x float4 loads/stores; 1 swizzled LDS trip.
// FUSE=1: fold last gray perm + expectation partials.
template<int FUSE>
__global__ __launch_bounds__(1024) void stageB(const float* __restrict__ x,
                                               float2* __restrict__ st,
                                               float* __restrict__ partial) {
    __shared__ float2 lds[4096];
    __shared__ float2 Gs[4*NW];
    const unsigned t = threadIdx.x;
    const unsigned lane = t & 63u, wv = t >> 6;
    const unsigned w0 = wv & 1u, w1 = (wv >> 1) & 1u, w2 = (wv >> 2) & 1u, w3 = wv >> 3;
    const unsigned l012 = lane & 7u;
    const unsigned l3 = (lane >> 3) & 1u, l4 = (lane >> 4) & 1u, l5 = lane >> 5;
    const unsigned bb = blockIdx.x;

    float4 qa, qb;                    // loads before prep (16B/lane)
    {
        const unsigned ba = (l012 << 1) | (bb << 4) | (l3 << 13) | (l4 << 14)
                          | (l5 << 15) | (w0 << 16) | (w1 << 17) | (w2 << 18) | (w3 << 19);
        qa = *(const float4*)(st + ba);
        qb = *(const float4*)(st + (ba | (1u << 12)));
    }
    prep_Gs(x, Gs, t);
    __syncthreads();

    float2 amp[4];                    // r = k0 | k1<<1 ; k0=z0, k1=z12
    amp[0] = make_float2(qa.x, qa.y); amp[1] = make_float2(qa.z, qa.w);
    amp[2] = make_float2(qb.x, qb.y); amp[3] = make_float2(qb.z, qb.w);

    gate_regbit<1>(amp, Gs + 7*4);    // b12 (k1=z12)
    swap_reg_lane4<1,8>(amp, lane);   // z12<->z13: k1=z13, l3=z12
    gate_regbit<1>(amp, Gs + 6*4);    // b13
    swap_reg_lane4<1,16>(amp, lane);  // z13<->z14: k1=z14, l4=z13
    gate_regbit<1>(amp, Gs + 5*4);    // b14
    swap_reg_lane4<1,32>(amp, lane);  // z14<->z15: k1=z15, l5=z14
    gate_regbit<1>(amp, Gs + 4*4);    // b15
    // map: k0=z0, k1=z15, l0..2=z1..3, l3=z12, l4=z13, l5=z14, wv=z16..19
    // swizzled single trip. write addr: a0..2=z1..3, a3=z12, a4=z13, a5=z14,
    // a6=z0, a7=z15, a8..11=z16..19
    #pragma unroll
    for (int k = 0; k < 4; k++)
        lds[swz(lane | ((unsigned)k << 6) | (wv << 8))] = amp[k];
    __syncthreads();
    // read: k1'=z16 (a8), l3'=z17 (a9), l4'=z18 (a10), l5'=z19 (a11),
    // waves pick up z12..15 (a3,a4,a5,a7); k0 stays z0 (a6)
    #pragma unroll
    for (int k = 0; k < 4; k++)
        amp[k] = lds[swz(l012 | (w0 << 3) | (w1 << 4) | (w2 << 5)
                         | ((unsigned)(k & 1) << 6) | (w3 << 7)
                         | ((unsigned)(k >> 1) << 8)
                         | (l3 << 9) | (l4 << 10) | (l5 << 11))];
    gate_regbit<1>(amp, Gs + 3*4);    // b16 (k1=z16)
    swap_reg_lane4<1,8>(amp, lane);   // z16<->z17: k1=z17, l3=z16
    gate_regbit<1>(amp, Gs + 2*4);    // b17
    swap_reg_lane4<1,16>(amp, lane);  // z17<->z18: k1=z18, l4=z17
    gate_regbit<1>(amp, Gs + 1*4);    // b18
    swap_reg_lane4<1,32>(amp, lane);  // z18<->z19: k1=z19, l5=z18
    gate_regbit<1>(amp, Gs + 0*4);    // b19
    // final map: k0=z0, k1=z19; l0..2=z1..3; l3=z16, l4=z17, l5=z18; wv=z12..15

    const unsigned sb = (l012 << 1) | (bb << 4) | (w0 << 12) | (w1 << 13)
                      | (w2 << 14) | (w3 << 15) | (l3 << 16) | (l4 << 17) | (l5 << 18);
    if (!FUSE) {
        *(float4*)(st + sb) =
            make_float4(amp[0].x, amp[0].y, amp[1].x, amp[1].y);
        *(float4*)(st + (sb | (1u << 19))) =
            make_float4(amp[2].x, amp[2].y, amp[3].x, amp[3].y);
    } else {
        // y = invgray(Y): y_b = XOR_{j>=b} Y_j. Per-thread amps differ in z0 (k0,
        // affects only y_0) and z19 (k1, affects every y_b).
        // wires 0..18 (b=19-w>=1): acc = (-1)^{v_b} * E, E = (p0+p1)-(p2+p3)
        // wire 19 (b=0):           acc = (-1)^{v_0} * D, D = p0-p1-p2+p3
        // v_b = XOR_{j=b..18} Y_j = sfx(Yp) bit b, Yp = Y with z0=z19=0 (== sb).
        float p[4];
        #pragma unroll
        for (int k = 0; k < 4; k++) p[k] = amp[k].x*amp[k].x + amp[k].y*amp[k].y;
        const float E = (p[0] + p[1]) - (p[2] + p[3]);
        const float D = p[0] - p[1] - p[2] + p[3];
        const unsigned cm = sfx(sb);
        float acc[NW];
        #pragma unroll
        for (int w = 0; w < 19; w++)
            acc[w] = ((cm >> (19 - w)) & 1u) ? -E : E;
        acc[19] = (cm & 1u) ? -D : D;

        __syncthreads();                 // LDS reads done; reuse for reduction
        float* red = (float*)lds;
        #pragma unroll
        for (int w = 0; w < NW; w++) {
            float s = acc[w];
            #pragma unroll
            for (int off = 32; off; off >>= 1) s += __shfl_down(s, off, 64);
            if (lane == 0) red[wv*NW + w] = s;
        }
        __syncthreads();
        if (t < NW) {
            float s = 0.0f;
            #pragma unroll
            for (int v16 = 0; v16 < 16; v16++) s += red[v16*NW + (int)t];
            partial[bb*NW + t] = s;
        }
    }
}

__global__ __launch_bounds__(256) void reduce_out(const float* __restrict__ partial,
                                                  float* __restrict__ out) {
    __shared__ float red[4*NW];
    unsigned t = threadIdx.x;
    float vals[NW];
    #pragma unroll
    for (int w = 0; w < NW; w++) vals[w] = partial[t*NW + w];
    #pragma unroll
    for (int w = 0; w < NW; w++) {
        float v = vals[w];
        #pragma unroll
        for (int off = 32; off; off >>= 1) v += __shfl_down(v, off, 64);
        if ((t & 63u) == 0u) red[(t >> 6)*NW + w] = v;
    }
    __syncthreads();
    if (t < NW) out[t] = red[t] + red[NW+t] + red[2*NW+t] + red[3*NW+t];
}

extern "C" void kernel_launch(void* const* d_in, const int* in_sizes, int n_in,
                              void* d_out, int out_size, void* d_ws, size_t ws_size,
                              hipStream_t stream) {
    (void)in_sizes; (void)n_in; (void)out_size; (void)ws_size;
    const float* x = (const float*)d_in[0];
    float* out = (float*)d_out;

    char* ws = (char*)d_ws;
    float*  partial = (float*)(ws + 1024);                        // 20 KB
    float2* buf0    = (float2*)(ws + 65536);                      // 8 MB
    float2* buf1    = (float2*)(ws + 65536 + (size_t)(8u << 20)); // 8 MB

    // layer 1 folded into product state; layer 2:
    stageA<0><<<256, 1024, 0, stream>>>(x, buf1 /*unused*/, buf0);
    stageB<0><<<256, 1024, 0, stream>>>(x, buf0, nullptr);
    // layer 3 (perm folded into A read):
    stageA<1><<<256, 1024, 0, stream>>>(x, buf0, buf1);
    stageB<0><<<256, 1024, 0, stream>>>(x, buf1, nullptr);
    // layer 4 (+ fused expectation, final perm folded):
    stageA<1><<<256, 1024, 0, stream>>>(x, buf1, buf0);
    stageB<1><<<256, 1024, 0, stream>>>(x, buf0, partial);
    reduce_out<<<1, 256, 0, stream>>>(partial, out);
}

// Round 15
// 63.641 us; speedup vs baseline: 1.2586x; 1.0664x over previous
//
#include <hip/hip_runtime.h>

// 20-qubit feature map, 4 layers (RX·RY per wire + CNOT chain), <Z_i> outputs.
// wire w <-> bit (19-w). CNOT chain == gray perm: new[y] = old[y ^ (y>>1)], folded
// into the next A read (MODE1) or final expectation (FUSE). Layer 1 on |0..0> is a
// product state computed in-register (MODE0).
// R15 = R8 VERBATIM (session best: 63.7us, absmax 0.0). Six gate passes + reduce;
// 1024 thr/block x 4 amps/thread (16 waves/CU); dispatch boundaries as the only
// cheap cross-XCD barrier. Every attempted deviation (R9-R14) regressed:
// packed math null; masked 4-pass fusion +16us; single-trip LDS +4..10us;
// grid.sync +29us/ea; device-scope ticket +62us.

#define NW 20

__device__ __forceinline__ float2 cmul(float2 a, float2 b) {
    return make_float2(a.x*b.x - a.y*b.y, a.x*b.y + a.y*b.x);
}

__device__ __forceinline__ void apply_gate(float2& a0, float2& a1,
                                           float2 u00, float2 u01,
                                           float2 u10, float2 u11) {
    float2 b0, b1;
    b0.x = u00.x*a0.x - u00.y*a0.y + u01.x*a1.x - u01.y*a1.y;
    b0.y = u00.x*a0.y + u00.y*a0.x + u01.x*a1.y + u01.y*a1.x;
    b1.x = u10.x*a0.x - u10.y*a0.y + u11.x*a1.x - u11.y*a1.y;
    b1.y = u10.x*a0.y + u10.y*a0.x + u11.x*a1.y + u11.y*a1.x;
    a0 = b0; a1 = b1;
}

__device__ __forceinline__ float2 shflx(float2 v, int m) {
    float2 r;
    r.x = __shfl_xor(v.x, m, 64);
    r.y = __shfl_xor(v.y, m, 64);
    return r;
}

// suffix-XOR: bit b of result = XOR_{j>=b} x_j
__device__ __forceinline__ unsigned sfx(unsigned x) {
    x ^= x >> 1; x ^= x >> 2; x ^= x >> 4; x ^= x >> 8; x ^= x >> 16; return x;
}

// plain gate pairing reg-bit A (4-amp variant of the R4-verified engine)
template<int A>
__device__ __forceinline__ void gate_regbit4(float2 (&amp)[4], const float2* Gw) {
    float2 u00 = Gw[0], u01 = Gw[1], u10 = Gw[2], u11 = Gw[3];
    #pragma unroll
    for (int r = 0; r < 4; r++)
        if (!(r & (1 << A)))
            apply_gate(amp[r], amp[r | (1 << A)], u00, u01, u10, u11);
}

// butterfly: swap reg-bit A with lane bit LM (R4-verified orientation)
template<int A, int LM>
__device__ __forceinline__ void swap_reg_lane4(float2 (&amp)[4], unsigned lane) {
    bool hb = (lane & (unsigned)LM) != 0u;
    #pragma unroll
    for (int r = 0; r < 4; r++) {
        if (!(r & (1 << A))) {
            float2 lo = amp[r], hi = amp[r | (1 << A)];
            float2 xs = hb ? lo : hi;
            float2 ys = shflx(xs, LM);
            amp[r]            = hb ? ys : lo;
            amp[r | (1 << A)] = hb ? hi : ys;
        }
    }
}

// per-block gate prep: U = RY(x)*RX(x), half-angle h = x/2
__device__ __forceinline__ void prep_Gs(const float* __restrict__ x, float2* Gs,
                                        unsigned t) {
    if (t < NW) {
        float h = 0.5f * x[t];
        float c = cosf(h), s = sinf(h);
        float cc = c*c, ss = s*s, cs = c*s;
        Gs[t*4+0] = make_float2(cc,  ss);
        Gs[t*4+1] = make_float2(-cs, -cs);
        Gs[t*4+2] = make_float2(cs,  -cs);
        Gs[t*4+3] = make_float2(cc,  -ss);
    }
}

// Stage A: gates on bits 0..11 (wires 19..8). Block = logical high byte H.
// Thread: regs = 2 bits (walking), lanes l0..5, waves w0..3. 4 amps/thread.
// MODE 0: product state (layer-1 folded). MODE 1: gray-fold read from src.
template<int MODE>
__global__ __launch_bounds__(1024) void stageA(const float* __restrict__ x,
                                               const float2* __restrict__ src,
                                               float2* __restrict__ dst) {
    __shared__ float2 lds[4096];
    __shared__ float2 Gs[4*NW];
    const unsigned t = threadIdx.x;
    prep_Gs(x, Gs, t);
    __syncthreads();
    const unsigned lane = t & 63u, wv = t >> 6;           // wv: 4 bits
    const unsigned w0 = wv & 1u, w1 = (wv >> 1) & 1u, w2 = (wv >> 2) & 1u, w3 = wv >> 3;
    const unsigned H   = blockIdx.x;
    const unsigned Hp  = H ^ (H >> 1);
    const unsigned inj = (H & 1u) << 11;
    const unsigned lb  = (wv << 8) | (lane << 2);         // logical low-12 base
    const unsigned gb  = (lb ^ (lb >> 1)) ^ inj;          // gray12 ^ inj; gb&3 in {0,2}

    float2 amp[4];
    if (MODE == 1) {
        // phys low-12 = gb ^ gray2(k); aligned 32B quad at gb&~3
        const float4* q = (const float4*)(src + ((size_t)Hp << 12) + (gb & ~3u));
        float4 q0 = q[0], q1 = q[1];
        float2 e0 = make_float2(q0.x,q0.y), e1 = make_float2(q0.z,q0.w);
        float2 e2 = make_float2(q1.x,q1.y), e3 = make_float2(q1.z,q1.w);
        bool s2 = (gb & 2u) != 0u;   // amp[k] = e[(gb&3) ^ gray2(k)], gray2: 0,1,3,2
        amp[0] = s2 ? e2 : e0;
        amp[1] = s2 ? e3 : e1;
        amp[2] = s2 ? e1 : e3;
        amp[3] = s2 ? e0 : e2;
    } else {
        // amp(Y) = prod_b U^{19-b}[z_b][0], z = gray20(Y)
        float2 P = make_float2(1.0f, 0.0f);
        #pragma unroll
        for (int b = 12; b <= 19; b++)
            P = cmul(P, Gs[(19-b)*4 + (int)((Hp >> (b-12)) & 1u)*2]);
        #pragma unroll
        for (int b = 2; b <= 11; b++)
            P = cmul(P, Gs[(19-b)*4 + (int)((gb >> b) & 1u)*2]);
        float2 T[4];
        #pragma unroll
        for (int j = 0; j < 4; j++)
            T[j] = cmul(P, cmul(Gs[19*4 + (j&1)*2], Gs[18*4 + ((j>>1)&1)*2]));
        bool s2 = (gb & 2u) != 0u;
        amp[0] = s2 ? T[2] : T[0];
        amp[1] = s2 ? T[3] : T[1];
        amp[2] = s2 ? T[1] : T[3];
        amp[3] = s2 ? T[0] : T[2];
    }

    gate_regbit4<0>(amp, Gs + 19*4);   // b0
    gate_regbit4<1>(amp, Gs + 18*4);   // b1
    swap_reg_lane4<0,1>(amp, lane);    // b0<->b2
    swap_reg_lane4<1,2>(amp, lane);    // b1<->b3
    gate_regbit4<0>(amp, Gs + 17*4);   // b2
    gate_regbit4<1>(amp, Gs + 16*4);   // b3
    swap_reg_lane4<0,4>(amp, lane);
    swap_reg_lane4<1,8>(amp, lane);
    gate_regbit4<0>(amp, Gs + 15*4);   // b4
    gate_regbit4<1>(amp, Gs + 14*4);   // b5
    swap_reg_lane4<0,16>(amp, lane);
    swap_reg_lane4<1,32>(amp, lane);
    gate_regbit4<0>(amp, Gs + 13*4);   // b6
    gate_regbit4<1>(amp, Gs + 12*4);   // b7
    // map: l=b0..5, regs={b6,b7}, wv=b8..11
    // X1: a0..5=b0..5, a6,a7=b6,b7, a8..11=b8..11
    #pragma unroll
    for (int k = 0; k < 4; k++) lds[lane | ((unsigned)k << 6) | (wv << 8)] = amp[k];
    __syncthreads();
    // read: regs={b8,b9}; w0,w1 keep b6,b7; w2,w3 = b10,b11
    #pragma unroll
    for (int k = 0; k < 4; k++)
        amp[k] = lds[lane | (w0 << 6) | (w1 << 7) | ((unsigned)k << 8) | (w2 << 10) | (w3 << 11)];
    gate_regbit4<0>(amp, Gs + 11*4);   // b8
    gate_regbit4<1>(amp, Gs + 10*4);   // b9
    __syncthreads();
    // X2: a6,a7=b8,b9 ; a8,a9=b6,b7 ; a10,a11=b10,b11
    #pragma unroll
    for (int k = 0; k < 4; k++) lds[lane | ((unsigned)k << 6) | (wv << 8)] = amp[k];
    __syncthreads();
    // read: regs={b10,b11}; w0,w1 keep b6,b7 (a8,a9); w2,w3 = b8,b9 (a6,a7)
    #pragma unroll
    for (int k = 0; k < 4; k++)
        amp[k] = lds[lane | (w2 << 6) | (w3 << 7) | (w0 << 8) | (w1 << 9) | ((unsigned)k << 10)];
    gate_regbit4<0>(amp, Gs + 9*4);    // b10
    gate_regbit4<1>(amp, Gs + 8*4);    // b11
    // store logical: Y = lane | b6,b7(w0,w1) | b8,b9(w2,w3) | b10,b11(k)
    float2* d = dst + ((size_t)H << 12);
    #pragma unroll
    for (int k = 0; k < 4; k++)
        d[lane | (w0 << 6) | (w1 << 7) | (w2 << 8) | (w3 << 9) | ((unsigned)k << 10)] = amp[k];
}

// Stage B: gates on bits 12..19 (wires 7..0), h = bits 12..19; in-place;
// block = bits 4..11 (bb); m = lane&15 = bits 0..3 (128B runs).
// FUSE=1: final layer -> fold last gray perm, accumulate <Z_w> partials.
template<int FUSE>
__global__ __launch_bounds__(1024) void stageB(const float* __restrict__ x,
                                               float2* __restrict__ st,
                                               float* __restrict__ partial) {
    __shared__ float2 lds[4096];
    __shared__ float2 Gs[4*NW];
    const unsigned t = threadIdx.x;
    prep_Gs(x, Gs, t);
    __syncthreads();
    const unsigned lane = t & 63u, wv = t >> 6;
    const unsigned w0 = wv & 1u, w1 = (wv >> 1) & 1u, w2 = (wv >> 2) & 1u, w3 = wv >> 3;
    const unsigned bb = blockIdx.x;
    const unsigned m = lane & 15u, l4 = (lane >> 4) & 1u, l5 = lane >> 5;

    // load: h = k(h0,h1) | l4(h2) | l5(h3) | wv(h4..7)
    float2 amp[4];
    #pragma unroll
    for (int k = 0; k < 4; k++) {
        unsigned h = (unsigned)k | (l4 << 2) | (l5 << 3) | (wv << 4);
        amp[k] = st[((size_t)h << 12) | (bb << 4) | m];
    }
    gate_regbit4<0>(amp, Gs + 7*4);    // h0 (b12, wire 7)
    gate_regbit4<1>(amp, Gs + 6*4);    // h1 (b13)
    swap_reg_lane4<0,16>(amp, lane);   // h0<->h2
    swap_reg_lane4<1,32>(amp, lane);   // h1<->h3
    gate_regbit4<0>(amp, Gs + 5*4);    // h2 (b14)
    gate_regbit4<1>(amp, Gs + 4*4);    // h3 (b15)
    // map: l4=h0, l5=h1, regs={h2,h3}, wv=h4..7
    // X1: a0..3=m, a4=h0, a5=h1, a6,a7=h2,h3, a8..11=h4..7
    #pragma unroll
    for (int k = 0; k < 4; k++) lds[lane | ((unsigned)k << 6) | (wv << 8)] = amp[k];
    __syncthreads();
    // read: regs={h4,h5}; w0,w1 = h2,h3; w2,w3 = h6,h7
    #pragma unroll
    for (int k = 0; k < 4; k++)
        amp[k] = lds[lane | (w0 << 6) | (w1 << 7) | ((unsigned)k << 8) | (w2 << 10) | (w3 << 11)];
    gate_regbit4<0>(amp, Gs + 3*4);    // h4 (b16)
    gate_regbit4<1>(amp, Gs + 2*4);    // h5 (b17)
    __syncthreads();
    // X2: a6,a7=h4,h5 ; a8,a9=h2,h3 ; a10,a11=h6,h7
    #pragma unroll
    for (int k = 0; k < 4; k++) lds[lane | ((unsigned)k << 6) | (wv << 8)] = amp[k];
    __syncthreads();
    // read: regs={h6,h7}; w0,w1 keep h2,h3 (a8,a9); w2,w3 = h4,h5 (a6,a7)
    #pragma unroll
    for (int k = 0; k < 4; k++)
        amp[k] = lds[lane | (w2 << 6) | (w3 << 7) | (w0 << 8) | (w1 << 9) | ((unsigned)k << 10)];
    gate_regbit4<0>(amp, Gs + 1*4);    // h6 (b18)
    gate_regbit4<1>(amp, Gs + 0*4);    // h7 (b19)
    // final map: l4=h0, l5=h1, w0=h2, w1=h3, w2=h4, w3=h5, k={h6,h7}

    if (!FUSE) {
        #pragma unroll
        for (int k = 0; k < 4; k++) {
            unsigned h = l4 | (l5 << 1) | (w0 << 2) | (w1 << 3) | (w2 << 4) | (w3 << 5)
                       | (((unsigned)k & 1u) << 6) | (((unsigned)k >> 1) << 7);
            st[((size_t)h << 12) | (bb << 4) | m] = amp[k];
        }
    } else {
        // y = invgray(Y); k0 = Y18, k1 = Y19.
        float p[4];
        #pragma unroll
        for (int k = 0; k < 4; k++) p[k] = amp[k].x*amp[k].x + amp[k].y*amp[k].y;
        float S19 = (p[0] + p[1]) - (p[2] + p[3]);      // (-1)^{Y19}
        float D   = p[0] - p[1] - p[2] + p[3];          // (-1)^{Y18^Y19}
        unsigned v = m | (bb << 4) | (l4 << 12) | (l5 << 13) | (w0 << 14)
                   | (w1 << 15) | (w2 << 16) | (w3 << 17);   // Y bits 0..17
        unsigned cm = sfx(v);                            // cm_b = XOR_{j=b..17} Y_j
        float acc[NW];
        acc[0] = S19; acc[1] = D;
        #pragma unroll
        for (int w = 2; w < NW; w++)
            acc[w] = ((cm >> (19 - w)) & 1u) ? -D : D;

        __syncthreads();                 // gate LDS reads done; reuse for reduction
        float* red = (float*)lds;
        #pragma unroll
        for (int w = 0; w < NW; w++) {
            float s = acc[w];
            #pragma unroll
            for (int off = 32; off; off >>= 1) s += __shfl_down(s, off, 64);
            if (lane == 0) red[wv*NW + w] = s;
        }
        __syncthreads();
        if (t < NW) {
            float s = 0.0f;
            #pragma unroll
            for (int v16 = 0; v16 < 16; v16++) s += red[v16*NW + (int)t];
            partial[bb*NW + t] = s;
        }
    }
}

__global__ __launch_bounds__(256) void reduce_out(const float* __restrict__ partial,
                                                  float* __restrict__ out) {
    __shared__ float red[4*NW];
    unsigned t = threadIdx.x;
    float vals[NW];
    #pragma unroll
    for (int w = 0; w < NW; w++) vals[w] = partial[t*NW + w];
    #pragma unroll
    for (int w = 0; w < NW; w++) {
        float v = vals[w];
        #pragma unroll
        for (int off = 32; off; off >>= 1) v += __shfl_down(v, off, 64);
        if ((t & 63u) == 0u) red[(t >> 6)*NW + w] = v;
    }
    __syncthreads();
    if (t < NW) out[t] = red[t] + red[NW+t] + red[2*NW+t] + red[3*NW+t];
}

extern "C" void kernel_launch(void* const* d_in, const int* in_sizes, int n_in,
                              void* d_out, int out_size, void* d_ws, size_t ws_size,
                              hipStream_t stream) {
    (void)in_sizes; (void)n_in; (void)out_size; (void)ws_size;
    const float* x = (const float*)d_in[0];
    float* out = (float*)d_out;

    char* ws = (char*)d_ws;
    float*  partial = (float*)(ws + 1024);                        // 20 KB
    float2* buf0    = (float2*)(ws + 65536);                      // 8 MB
    float2* buf1    = (float2*)(ws + 65536 + (size_t)(8u << 20)); // 8 MB

    // layer 1 folded into product state; layer 2:
    stageA<0><<<256, 1024, 0, stream>>>(x, buf1 /*unused*/, buf0);
    stageB<0><<<256, 1024, 0, stream>>>(x, buf0, nullptr);
    // layer 3 (perm folded into A read):
    stageA<1><<<256, 1024, 0, stream>>>(x, buf0, buf1);
    stageB<0><<<256, 1024, 0, stream>>>(x, buf1, nullptr);
    // layer 4 (+ fused expectation, final perm folded):
    stageA<1><<<256, 1024, 0, stream>>>(x, buf1, buf0);
    stageB<1><<<256, 1024, 0, stream>>>(x, buf0, partial);
    reduce_out<<<1, 256, 0, stream>>>(partial, out);
}